// Round 4
// baseline (447.000 us; speedup 1.0000x reference)
//
#include <hip/hip_runtime.h>
#include <math.h>

// ---------------------------------------------------------------------------
// AFNO3D + LoRA, B=4 H=W=L=64 C=64, modes kh<32 kw<32 kl<8, NB=8 BS=8 R=8.
//
// 3-kernel pipeline (intermediates in d_ws):
//   K1: per (b,h,c-half): DFT-L (real->8 modes) -> LDS slab -> DFT-W (->32)
//   K2: per (b,kw,kl): DFT-H + block-diag complex MLP (LoRA) + iDFT-H in LDS
//   K3: per (b,h,c-half): stage z2 slab -> iDFT-W (regs) -> iDFT-L + residual
//
// R4 change: all in-loop twiddle LDS lookups replaced by register rotation
// recurrences (f *= e^{+-i 2pi k/64} per step) — removes the lgkmcnt-latency
// critical path that made k1 latency-bound (198 us @ 10% HBM, 49% VALU).
// fp32 throughout. Ortho scaling: 1/512 in K2 (pre-MLP) and 1/512 in K3.
// ---------------------------------------------------------------------------

#define PI2_64 0.09817477042468103f   // 2*pi/64

__device__ __forceinline__ float gelu_exact(float t) {
    return 0.5f * t * (1.0f + erff(t * 0.7071067811865475f));
}

// ===========================================================================
// K1: fused DFT-L + DFT-W.  Block = (b, h, ch); 1024 threads.
__global__ void __launch_bounds__(1024) k1_lw(const float* __restrict__ x,
                                              float* __restrict__ y2f) {
    __shared__ float2 tw[64];
    __shared__ float4 sY[8 * 16 * 65];   // 133120 B
    int tid = threadIdx.x;
    if (tid < 64) {
        float s, c;
        sincosf(PI2_64 * (float)tid, &s, &c);
        tw[tid] = make_float2(c, s);
    }
    __syncthreads();

    int bid = blockIdx.x;
    int b = bid >> 7, h = (bid >> 1) & 63, ch = bid & 1;
    int c0 = ch * 32;

    {   // ---- phase 1: DFT along L, twiddles rotate in registers ----
        int cp = tid & 15, w = tid >> 4;
        const float* xp = x + ((size_t)((b * 64 + h) * 64 + w) * 64) * 64 + c0 + 2 * cp;
        float2 ar[8], ai[8];   // [kl]: (re_c0, re_c1), (im_c0, im_c1)
        float2 f[8], st[8];    // f = e^{-i 2pi l*kl/64}; st = per-l step
#pragma unroll
        for (int kl = 0; kl < 8; ++kl) {
            ar[kl] = make_float2(0.f, 0.f);
            ai[kl] = make_float2(0.f, 0.f);
            f[kl]  = make_float2(1.f, 0.f);
            float2 t = tw[kl];
            st[kl] = make_float2(t.x, -t.y);       // e^{-i 2pi kl/64}
        }
        for (int l = 0; l < 64; ++l) {
            float2 v = *(const float2*)(xp + l * 64);
#pragma unroll
            for (int kl = 0; kl < 8; ++kl) {
                ar[kl].x += v.x * f[kl].x;  ai[kl].x += v.x * f[kl].y;
                ar[kl].y += v.y * f[kl].x;  ai[kl].y += v.y * f[kl].y;
                if (kl) {   // kl=0: f stays (1,0)
                    float nr = f[kl].x * st[kl].x - f[kl].y * st[kl].y;
                    float ni = f[kl].y * st[kl].x + f[kl].x * st[kl].y;
                    f[kl] = make_float2(nr, ni);
                }
            }
        }
#pragma unroll
        for (int kl = 0; kl < 8; ++kl)
            sY[(kl * 16 + cp) * 65 + w] =
                make_float4(ar[kl].x, ai[kl].x, ar[kl].y, ai[kl].y);
    }
    __syncthreads();

    {   // ---- phase 2: DFT along W (64 -> 32), twiddles rotate in regs ----
        int cp = tid & 15, kl = (tid >> 4) & 7, kwq = tid >> 7;
        const float4* row = &sY[(kl * 16 + cp) * 65];
        float4 acc[4];
        float2 f2r[4], s2[4];   // f = e^{-i 2pi w*kw/64}
#pragma unroll
        for (int i = 0; i < 4; ++i) {
            acc[i] = make_float4(0.f, 0.f, 0.f, 0.f);
            f2r[i] = make_float2(1.f, 0.f);
            float2 t = tw[kwq * 4 + i];
            s2[i] = make_float2(t.x, -t.y);
        }
        for (int w = 0; w < 64; ++w) {
            float4 d = row[w];
#pragma unroll
            for (int i = 0; i < 4; ++i) {
                acc[i].x += d.x * f2r[i].x - d.y * f2r[i].y;
                acc[i].y += d.y * f2r[i].x + d.x * f2r[i].y;
                acc[i].z += d.z * f2r[i].x - d.w * f2r[i].y;
                acc[i].w += d.w * f2r[i].x + d.z * f2r[i].y;
                float nr = f2r[i].x * s2[i].x - f2r[i].y * s2[i].y;
                float ni = f2r[i].y * s2[i].x + f2r[i].x * s2[i].y;
                f2r[i] = make_float2(nr, ni);
            }
        }
        float4* y2 = (float4*)y2f;
#pragma unroll
        for (int i = 0; i < 4; ++i) {
            int kw = kwq * 4 + i;
            y2[(size_t)(((b * 8 + kl) * 32 + kw) * 64 + h) * 32 + ch * 16 + cp] = acc[i];
        }
    }
}

// ===========================================================================
// K2: fused DFT-H (64->32, *1/512) + block-diag complex MLP + iDFT-H (32->64).
// One block per (b,kw,kl). Validated in R2/R3 (unchanged).
__global__ void __launch_bounds__(256) kc_h_mlp(
        const float* __restrict__ y2f, float* __restrict__ z2f,
        const float* __restrict__ w1, const float* __restrict__ b1,
        const float* __restrict__ w2, const float* __restrict__ b2,
        const float* __restrict__ la1rA, const float* __restrict__ la1rB,
        const float* __restrict__ la1iA, const float* __restrict__ la1iB,
        const float* __restrict__ la2rA, const float* __restrict__ la2rB,
        const float* __restrict__ la2iA, const float* __restrict__ la2iB) {
    __shared__ float2 sD[64][64];      // staged input; reused as sM2[32][66]
    __shared__ float2 sT[64][34];      // e^{-2pi i h*kh/64} at [h][kh] (kh<32)
    __shared__ float2 sM[32][66];
    __shared__ float  sW[4][512];
    __shared__ float  sb1[128], sb2[128];
    int tid = threadIdx.x;
    int pos = blockIdx.x;              // (b*32+kw)*8 + kl
    int kl = pos & 7, kw = (pos >> 3) & 31, b = pos >> 8;

#pragma unroll
    for (int r = 0; r < 8; ++r) {
        int idx = r * 256 + tid;
        int h = idx >> 5, kh = idx & 31;
        float sn, cs;
        sincosf(PI2_64 * (float)((h * kh) & 63), &sn, &cs);
        sT[h][kh] = make_float2(cs, -sn);
    }
    const float2* src = (const float2*)y2f + (size_t)((b * 8 + kl) * 32 + kw) * 4096;
#pragma unroll
    for (int r = 0; r < 8; ++r) {
        int f = r * 512 + tid * 2;
        *(float4*)(&sD[f >> 6][f & 63]) = *(const float4*)(src + f);
    }
    {   // LoRA-corrected weights
        const float* As[4]   = {la1rA, la1iA, la2rA, la2iA};
        const float* Bs[4]   = {la1rB, la1iB, la2rB, la2iB};
        const float* base[4] = {w1, w1 + 512, w2, w2 + 512};
#pragma unroll
        for (int e = 0; e < 8; ++e) {
            int flat = tid + e * 256;
            int mat = flat >> 9;
            int rem = flat & 511;
            int n = rem >> 6, i = (rem >> 3) & 7, o = rem & 7;
            const float* A  = As[mat] + n * 64 + i * 8;
            const float* Bp = Bs[mat] + n * 64 + o;
            float s = 0.f;
#pragma unroll
            for (int r = 0; r < 8; ++r) s += A[r] * Bp[r * 8];
            sW[mat][(i * 8 + o) * 8 + n] = base[mat][n * 64 + i * 8 + o] + 0.125f * s;
        }
        if (tid < 128) sb1[tid] = b1[tid];
        else           sb2[tid - 128] = b2[tid - 128];
    }
    __syncthreads();

    // ---- M[kh][c] = (1/512) * sum_h T[h][kh] * D[h][c], tile 4kh x 2c ----
    {
        int kh0 = (tid >> 5) * 4;
        int c0  = (tid & 31) * 2;
        float mr[4][2], mi[4][2];
#pragma unroll
        for (int i = 0; i < 4; ++i)
#pragma unroll
            for (int j = 0; j < 2; ++j) { mr[i][j] = 0.f; mi[i][j] = 0.f; }
        for (int h = 0; h < 64; ++h) {
            const float4* tT = (const float4*)(&sT[h][kh0]);
            float4 u0 = tT[0], u1 = tT[1];
            float4 d0 = *(const float4*)(&sD[h][c0]);
            float Tr[4] = {u0.x, u0.z, u1.x, u1.z};
            float Ti[4] = {u0.y, u0.w, u1.y, u1.w};
            float Dr[2] = {d0.x, d0.z};
            float Di[2] = {d0.y, d0.w};
#pragma unroll
            for (int i = 0; i < 4; ++i)
#pragma unroll
                for (int j = 0; j < 2; ++j) {
                    mr[i][j] += Tr[i] * Dr[j] - Ti[i] * Di[j];
                    mi[i][j] += Tr[i] * Di[j] + Ti[i] * Dr[j];
                }
        }
        const float sc = 1.0f / 512.0f;
#pragma unroll
        for (int i = 0; i < 4; ++i)
#pragma unroll
            for (int j = 0; j < 2; ++j)
                sM[kh0 + i][c0 + j] = make_float2(mr[i][j] * sc, mi[i][j] * sc);
    }
    __syncthreads();

    // ---- MLP per (kh, n) ----
    float2* sM2 = (float2*)&sD[0][0];   // [32][66]
    {
        int kh = tid >> 3, n = tid & 7;
        float xr[8], xi[8];
#pragma unroll
        for (int i = 0; i < 8; ++i) {
            float2 v = sM[kh][n * 8 + i];
            xr[i] = v.x; xi[i] = v.y;
        }
        float o1r[8], o1i[8];
#pragma unroll
        for (int o = 0; o < 8; ++o) {
            float br = sb1[n * 8 + o], bi = sb1[64 + n * 8 + o];
            float sr = br - bi, si = br + bi;
#pragma unroll
            for (int i = 0; i < 8; ++i) {
                float wr = sW[0][(i * 8 + o) * 8 + n];
                float wi = sW[1][(i * 8 + o) * 8 + n];
                sr += xr[i] * wr - xi[i] * wi;
                si += xi[i] * wr + xr[i] * wi;
            }
            o1r[o] = gelu_exact(sr);
            o1i[o] = gelu_exact(si);
        }
#pragma unroll
        for (int o = 0; o < 8; ++o) {
            float br = sb2[n * 8 + o], bi = sb2[64 + n * 8 + o];
            float sr = br - bi, si = br + bi;
#pragma unroll
            for (int i = 0; i < 8; ++i) {
                float wr = sW[2][(i * 8 + o) * 8 + n];
                float wi = sW[3][(i * 8 + o) * 8 + n];
                sr += o1r[i] * wr - o1i[i] * wi;
                si += o1i[i] * wr + o1r[i] * wi;
            }
            sM2[kh * 66 + n * 8 + o] = make_float2(sr, si);
        }
    }
    __syncthreads();

    // ---- out[h][c] = sum_kh conj(T[h][kh]) * M2[kh][c], tile 4h x 4c ----
    {
        int h0 = (tid >> 4) * 4;
        int c0 = (tid & 15) * 4;
        float orr[4][4], oii[4][4];
#pragma unroll
        for (int i = 0; i < 4; ++i)
#pragma unroll
            for (int j = 0; j < 4; ++j) { orr[i][j] = 0.f; oii[i][j] = 0.f; }
        for (int kh = 0; kh < 32; ++kh) {
            float2 T0 = sT[h0 + 0][kh];
            float2 T1 = sT[h0 + 1][kh];
            float2 T2 = sT[h0 + 2][kh];
            float2 T3 = sT[h0 + 3][kh];
            float Tr[4] = {T0.x, T1.x, T2.x, T3.x};
            float Ti[4] = {T0.y, T1.y, T2.y, T3.y};
            const float4* tM = (const float4*)(sM2 + kh * 66 + c0);
            float4 m0 = tM[0], m1 = tM[1];
            float Mr[4] = {m0.x, m0.z, m1.x, m1.z};
            float Mi[4] = {m0.y, m0.w, m1.y, m1.w};
#pragma unroll
            for (int i = 0; i < 4; ++i)
#pragma unroll
                for (int j = 0; j < 4; ++j) {
                    orr[i][j] += Tr[i] * Mr[j] + Ti[i] * Mi[j];
                    oii[i][j] += Tr[i] * Mi[j] - Ti[i] * Mr[j];
                }
        }
        float2* dst = (float2*)z2f + (size_t)((b * 8 + kl) * 32 + kw) * 4096;
#pragma unroll
        for (int i = 0; i < 4; ++i) {
            float4* d4 = (float4*)(dst + (h0 + i) * 64 + c0);
            d4[0] = make_float4(orr[i][0], oii[i][0], orr[i][1], oii[i][1]);
            d4[1] = make_float4(orr[i][2], oii[i][2], orr[i][3], oii[i][3]);
        }
    }
}

// ===========================================================================
// K3: fused iDFT-W + iDFT-L + residual.  Block = (b, h, ch); 1024 threads.
__global__ void __launch_bounds__(1024) k3_wl(const float* __restrict__ x,
                                              const float* __restrict__ z2f,
                                              float* __restrict__ outp) {
    __shared__ float2 tw[64];
    __shared__ float4 sZ[8 * 32 * 16];   // 64 KB, [kl][kw][cp]
    int tid = threadIdx.x;
    int bid = blockIdx.x;
    int b = bid >> 7, h = (bid >> 1) & 63, ch = bid & 1;
    int c0 = ch * 32;

    if (tid < 64) {
        float s, c;
        sincosf(PI2_64 * (float)tid, &s, &c);
        tw[tid] = make_float2(c, s);
    }
    const float4* z2 = (const float4*)z2f;
    __syncthreads();   // tw ready before staging loop reads it below
#pragma unroll
    for (int k = 0; k < 4; ++k) {
        int idx = k * 1024 + tid;        // 0..4095 = klkw*16 + cp
        int klkw = idx >> 4, cp = idx & 15;
        sZ[idx] = z2[(size_t)((b * 256 + klkw) * 64 + h) * 32 + ch * 16 + cp];
    }
    __syncthreads();

    int cp = tid & 15, w = tid >> 4;

    // ---- iDFT-W into registers: zw[kl] = sum_kw e^{+2pi i kw w/64} * Z ----
    float4 zw[8];
#pragma unroll
    for (int kl = 0; kl < 8; ++kl) zw[kl] = make_float4(0.f, 0.f, 0.f, 0.f);
    float2 u  = make_float2(1.f, 0.f);
    float2 su = tw[w];                   // e^{+2pi i w/64}
    for (int kw = 0; kw < 32; ++kw) {
#pragma unroll
        for (int kl = 0; kl < 8; ++kl) {
            float4 d = sZ[(kl * 32 + kw) * 16 + cp];
            zw[kl].x += d.x * u.x - d.y * u.y;
            zw[kl].y += d.y * u.x + d.x * u.y;
            zw[kl].z += d.z * u.x - d.w * u.y;
            zw[kl].w += d.w * u.x + d.z * u.y;
        }
        float nr = u.x * su.x - u.y * su.y;
        float ni = u.y * su.x + u.x * su.y;
        u = make_float2(nr, ni);
    }

    // ---- iDFT-L + residual, streaming over l; twiddles rotate in regs ----
    float z0r0 = zw[0].x, z0r1 = zw[0].z;
#pragma unroll
    for (int kl = 1; kl < 8; ++kl) {     // pre-double modes 1..7
        zw[kl].x *= 2.f; zw[kl].y *= 2.f; zw[kl].z *= 2.f; zw[kl].w *= 2.f;
    }
    float2 g[8], sg[8];                  // g = e^{+2pi i l*kl/64}
#pragma unroll
    for (int kl = 1; kl < 8; ++kl) {
        g[kl]  = make_float2(1.f, 0.f);
        sg[kl] = tw[kl];
    }
    const float* xp = x + ((size_t)((b * 64 + h) * 64 + w) * 64) * 64 + c0 + 2 * cp;
    float* op = outp + ((size_t)((b * 64 + h) * 64 + w) * 64) * 64 + c0 + 2 * cp;
    const float sc = 1.0f / 512.0f;
    for (int l = 0; l < 64; ++l) {
        float s0 = z0r0;
        float s1 = z0r1;
#pragma unroll
        for (int kl = 1; kl < 8; ++kl) {
            s0 += zw[kl].x * g[kl].x - zw[kl].y * g[kl].y;
            s1 += zw[kl].z * g[kl].x - zw[kl].w * g[kl].y;
            float nr = g[kl].x * sg[kl].x - g[kl].y * sg[kl].y;
            float ni = g[kl].y * sg[kl].x + g[kl].x * sg[kl].y;
            g[kl] = make_float2(nr, ni);
        }
        float2 xv = *(const float2*)(xp + l * 64);
        *(float2*)(op + l * 64) = make_float2(s0 * sc + xv.x, s1 * sc + xv.y);
    }
}

// ===========================================================================
extern "C" void kernel_launch(void* const* d_in, const int* in_sizes, int n_in,
                              void* d_out, int out_size, void* d_ws, size_t ws_size,
                              hipStream_t stream) {
    const float* x     = (const float*)d_in[0];
    const float* w1    = (const float*)d_in[1];
    const float* b1    = (const float*)d_in[2];
    const float* w2    = (const float*)d_in[3];
    const float* b2    = (const float*)d_in[4];
    const float* la1rA = (const float*)d_in[5];
    const float* la1rB = (const float*)d_in[6];
    const float* la1iA = (const float*)d_in[7];
    const float* la1iB = (const float*)d_in[8];
    const float* la2rA = (const float*)d_in[9];
    const float* la2rB = (const float*)d_in[10];
    const float* la2iA = (const float*)d_in[11];
    const float* la2iB = (const float*)d_in[12];
    float* out = (float*)d_out;

    float* ws = (float*)d_ws;
    float* y2 = ws;                    // [4][8][32][64][64] complex = 33 MB
    float* z2 = ws + 8388608;          // same

    hipLaunchKernelGGL(k1_lw,    dim3(512),  dim3(1024), 0, stream, x, y2);
    hipLaunchKernelGGL(kc_h_mlp, dim3(1024), dim3(256),  0, stream, y2, z2,
                       w1, b1, w2, b2, la1rA, la1rB, la1iA, la1iB,
                       la2rA, la2rB, la2iA, la2iB);
    hipLaunchKernelGGL(k3_wl,    dim3(512),  dim3(1024), 0, stream, x, z2, out);
}

// Round 5
// 438.843 us; speedup vs baseline: 1.0186x; 1.0186x over previous
//
#include <hip/hip_runtime.h>
#include <math.h>

// ---------------------------------------------------------------------------
// AFNO3D + LoRA, B=4 H=W=L=64 C=64, modes kh<32 kw<32 kl<8, NB=8 BS=8 R=8.
//
// 3-kernel pipeline (intermediates in d_ws):
//   K1: per (b,h,c-half): DFT-L (real->8 modes) -> LDS slab -> DFT-W (->32)
//   K2: per (b,kw,kl): DFT-H + block-diag complex MLP (LoRA) + iDFT-H in LDS
//   K3: per (b,h,c-half): stage z2 slab -> iDFT-W (regs) -> iDFT-L + residual
//
// R5 change (vs R3 baseline; R4's rotation recurrence spilled and is gone):
//  * twiddle tables twT[k][l] = e(k*l/64): in-loop reads are row-base +
//    immediate offset (zero address VALU) and wave-uniform (LDS broadcast).
//  * inner loops unrolled x4 with batched global loads (ILP latency hiding).
//  * k1/k3 __launch_bounds__(1024,4): VGPR cap 128, no spill (k1 is
//    LDS-capped at 1 block/CU regardless).
// fp32 throughout. Ortho scaling: 1/512 in K2 (pre-MLP) and 1/512 in K3.
// ---------------------------------------------------------------------------

#define PI2_64 0.09817477042468103f   // 2*pi/64

__device__ __forceinline__ float gelu_exact(float t) {
    return 0.5f * t * (1.0f + erff(t * 0.7071067811865475f));
}

// ===========================================================================
// K1: fused DFT-L + DFT-W.  Block = (b, h, ch); 1024 threads.
__global__ void __launch_bounds__(1024, 4) k1_lw(const float* __restrict__ x,
                                                 float* __restrict__ y2f) {
    __shared__ float2 twT[32][64];       // twT[k][l] = (cos,sin)(2pi k l/64)
    __shared__ float4 sY[8 * 16 * 65];   // 133120 B
    int tid = threadIdx.x;
#pragma unroll
    for (int e = 0; e < 2; ++e) {
        int idx = e * 1024 + tid;
        int k = idx >> 6, l = idx & 63;
        float s, c;
        sincosf(PI2_64 * (float)((k * l) & 63), &s, &c);
        twT[k][l] = make_float2(c, s);
    }
    __syncthreads();

    int bid = blockIdx.x;
    int b = bid >> 7, h = (bid >> 1) & 63, ch = bid & 1;
    int c0 = ch * 32;

    {   // ---- phase 1: DFT along L (8 modes), unroll l x4 ----
        int cp = tid & 15, w = tid >> 4;
        const float* xp = x + ((size_t)((b * 64 + h) * 64 + w) * 64) * 64 + c0 + 2 * cp;
        float4 A[8];   // [kl] = (re_c0, im_c0, re_c1, im_c1)
#pragma unroll
        for (int kl = 0; kl < 8; ++kl) A[kl] = make_float4(0.f, 0.f, 0.f, 0.f);
        for (int l0 = 0; l0 < 64; l0 += 4) {
            float2 v0 = *(const float2*)(xp + (l0 + 0) * 64);
            float2 v1 = *(const float2*)(xp + (l0 + 1) * 64);
            float2 v2 = *(const float2*)(xp + (l0 + 2) * 64);
            float2 v3 = *(const float2*)(xp + (l0 + 3) * 64);
#pragma unroll
            for (int kl = 0; kl < 8; ++kl) {
                float2 t0 = twT[kl][l0 + 0];
                float2 t1 = twT[kl][l0 + 1];
                float2 t2 = twT[kl][l0 + 2];
                float2 t3 = twT[kl][l0 + 3];
                A[kl].x += v0.x * t0.x;  A[kl].y -= v0.x * t0.y;
                A[kl].z += v0.y * t0.x;  A[kl].w -= v0.y * t0.y;
                A[kl].x += v1.x * t1.x;  A[kl].y -= v1.x * t1.y;
                A[kl].z += v1.y * t1.x;  A[kl].w -= v1.y * t1.y;
                A[kl].x += v2.x * t2.x;  A[kl].y -= v2.x * t2.y;
                A[kl].z += v2.y * t2.x;  A[kl].w -= v2.y * t2.y;
                A[kl].x += v3.x * t3.x;  A[kl].y -= v3.x * t3.y;
                A[kl].z += v3.y * t3.x;  A[kl].w -= v3.y * t3.y;
            }
        }
#pragma unroll
        for (int kl = 0; kl < 8; ++kl)
            sY[(kl * 16 + cp) * 65 + w] = A[kl];
    }
    __syncthreads();

    {   // ---- phase 2: DFT along W (64 -> 32), unroll w x4 ----
        int cp = tid & 15, kl = (tid >> 4) & 7, kwq = tid >> 7;
        const float4* row = &sY[(kl * 16 + cp) * 65];
        float4 acc[4];
#pragma unroll
        for (int i = 0; i < 4; ++i) acc[i] = make_float4(0.f, 0.f, 0.f, 0.f);
        for (int w0 = 0; w0 < 64; w0 += 4) {
            float4 d0 = row[w0 + 0];
            float4 d1 = row[w0 + 1];
            float4 d2 = row[w0 + 2];
            float4 d3 = row[w0 + 3];
#pragma unroll
            for (int i = 0; i < 4; ++i) {
                int kw = kwq * 4 + i;
                float2 t0 = twT[kw][w0 + 0];
                float2 t1 = twT[kw][w0 + 1];
                float2 t2 = twT[kw][w0 + 2];
                float2 t3 = twT[kw][w0 + 3];
                acc[i].x += d0.x * t0.x + d0.y * t0.y;   // * e^{-i th}
                acc[i].y += d0.y * t0.x - d0.x * t0.y;
                acc[i].z += d0.z * t0.x + d0.w * t0.y;
                acc[i].w += d0.w * t0.x - d0.z * t0.y;
                acc[i].x += d1.x * t1.x + d1.y * t1.y;
                acc[i].y += d1.y * t1.x - d1.x * t1.y;
                acc[i].z += d1.z * t1.x + d1.w * t1.y;
                acc[i].w += d1.w * t1.x - d1.z * t1.y;
                acc[i].x += d2.x * t2.x + d2.y * t2.y;
                acc[i].y += d2.y * t2.x - d2.x * t2.y;
                acc[i].z += d2.z * t2.x + d2.w * t2.y;
                acc[i].w += d2.w * t2.x - d2.z * t2.y;
                acc[i].x += d3.x * t3.x + d3.y * t3.y;
                acc[i].y += d3.y * t3.x - d3.x * t3.y;
                acc[i].z += d3.z * t3.x + d3.w * t3.y;
                acc[i].w += d3.w * t3.x - d3.z * t3.y;
            }
        }
        float4* y2 = (float4*)y2f;
#pragma unroll
        for (int i = 0; i < 4; ++i) {
            int kw = kwq * 4 + i;
            y2[(size_t)(((b * 8 + kl) * 32 + kw) * 64 + h) * 32 + ch * 16 + cp] = acc[i];
        }
    }
}

// ===========================================================================
// K2: fused DFT-H (64->32, *1/512) + block-diag complex MLP + iDFT-H (32->64).
// One block per (b,kw,kl). Validated in R2/R3/R4 (unchanged).
__global__ void __launch_bounds__(256) kc_h_mlp(
        const float* __restrict__ y2f, float* __restrict__ z2f,
        const float* __restrict__ w1, const float* __restrict__ b1,
        const float* __restrict__ w2, const float* __restrict__ b2,
        const float* __restrict__ la1rA, const float* __restrict__ la1rB,
        const float* __restrict__ la1iA, const float* __restrict__ la1iB,
        const float* __restrict__ la2rA, const float* __restrict__ la2rB,
        const float* __restrict__ la2iA, const float* __restrict__ la2iB) {
    __shared__ float2 sD[64][64];      // staged input; reused as sM2[32][66]
    __shared__ float2 sT[64][34];      // e^{-2pi i h*kh/64} at [h][kh] (kh<32)
    __shared__ float2 sM[32][66];
    __shared__ float  sW[4][512];
    __shared__ float  sb1[128], sb2[128];
    int tid = threadIdx.x;
    int pos = blockIdx.x;              // (b*32+kw)*8 + kl
    int kl = pos & 7, kw = (pos >> 3) & 31, b = pos >> 8;

#pragma unroll
    for (int r = 0; r < 8; ++r) {
        int idx = r * 256 + tid;
        int h = idx >> 5, kh = idx & 31;
        float sn, cs;
        sincosf(PI2_64 * (float)((h * kh) & 63), &sn, &cs);
        sT[h][kh] = make_float2(cs, -sn);
    }
    const float2* src = (const float2*)y2f + (size_t)((b * 8 + kl) * 32 + kw) * 4096;
#pragma unroll
    for (int r = 0; r < 8; ++r) {
        int f = r * 512 + tid * 2;
        *(float4*)(&sD[f >> 6][f & 63]) = *(const float4*)(src + f);
    }
    {   // LoRA-corrected weights
        const float* As[4]   = {la1rA, la1iA, la2rA, la2iA};
        const float* Bs[4]   = {la1rB, la1iB, la2rB, la2iB};
        const float* base[4] = {w1, w1 + 512, w2, w2 + 512};
#pragma unroll
        for (int e = 0; e < 8; ++e) {
            int flat = tid + e * 256;
            int mat = flat >> 9;
            int rem = flat & 511;
            int n = rem >> 6, i = (rem >> 3) & 7, o = rem & 7;
            const float* A  = As[mat] + n * 64 + i * 8;
            const float* Bp = Bs[mat] + n * 64 + o;
            float s = 0.f;
#pragma unroll
            for (int r = 0; r < 8; ++r) s += A[r] * Bp[r * 8];
            sW[mat][(i * 8 + o) * 8 + n] = base[mat][n * 64 + i * 8 + o] + 0.125f * s;
        }
        if (tid < 128) sb1[tid] = b1[tid];
        else           sb2[tid - 128] = b2[tid - 128];
    }
    __syncthreads();

    // ---- M[kh][c] = (1/512) * sum_h T[h][kh] * D[h][c], tile 4kh x 2c ----
    {
        int kh0 = (tid >> 5) * 4;
        int c0  = (tid & 31) * 2;
        float mr[4][2], mi[4][2];
#pragma unroll
        for (int i = 0; i < 4; ++i)
#pragma unroll
            for (int j = 0; j < 2; ++j) { mr[i][j] = 0.f; mi[i][j] = 0.f; }
        for (int h = 0; h < 64; ++h) {
            const float4* tT = (const float4*)(&sT[h][kh0]);
            float4 u0 = tT[0], u1 = tT[1];
            float4 d0 = *(const float4*)(&sD[h][c0]);
            float Tr[4] = {u0.x, u0.z, u1.x, u1.z};
            float Ti[4] = {u0.y, u0.w, u1.y, u1.w};
            float Dr[2] = {d0.x, d0.z};
            float Di[2] = {d0.y, d0.w};
#pragma unroll
            for (int i = 0; i < 4; ++i)
#pragma unroll
                for (int j = 0; j < 2; ++j) {
                    mr[i][j] += Tr[i] * Dr[j] - Ti[i] * Di[j];
                    mi[i][j] += Tr[i] * Di[j] + Ti[i] * Dr[j];
                }
        }
        const float sc = 1.0f / 512.0f;
#pragma unroll
        for (int i = 0; i < 4; ++i)
#pragma unroll
            for (int j = 0; j < 2; ++j)
                sM[kh0 + i][c0 + j] = make_float2(mr[i][j] * sc, mi[i][j] * sc);
    }
    __syncthreads();

    // ---- MLP per (kh, n) ----
    float2* sM2 = (float2*)&sD[0][0];   // [32][66]
    {
        int kh = tid >> 3, n = tid & 7;
        float xr[8], xi[8];
#pragma unroll
        for (int i = 0; i < 8; ++i) {
            float2 v = sM[kh][n * 8 + i];
            xr[i] = v.x; xi[i] = v.y;
        }
        float o1r[8], o1i[8];
#pragma unroll
        for (int o = 0; o < 8; ++o) {
            float br = sb1[n * 8 + o], bi = sb1[64 + n * 8 + o];
            float sr = br - bi, si = br + bi;
#pragma unroll
            for (int i = 0; i < 8; ++i) {
                float wr = sW[0][(i * 8 + o) * 8 + n];
                float wi = sW[1][(i * 8 + o) * 8 + n];
                sr += xr[i] * wr - xi[i] * wi;
                si += xi[i] * wr + xr[i] * wi;
            }
            o1r[o] = gelu_exact(sr);
            o1i[o] = gelu_exact(si);
        }
#pragma unroll
        for (int o = 0; o < 8; ++o) {
            float br = sb2[n * 8 + o], bi = sb2[64 + n * 8 + o];
            float sr = br - bi, si = br + bi;
#pragma unroll
            for (int i = 0; i < 8; ++i) {
                float wr = sW[2][(i * 8 + o) * 8 + n];
                float wi = sW[3][(i * 8 + o) * 8 + n];
                sr += o1r[i] * wr - o1i[i] * wi;
                si += o1i[i] * wr + o1r[i] * wi;
            }
            sM2[kh * 66 + n * 8 + o] = make_float2(sr, si);
        }
    }
    __syncthreads();

    // ---- out[h][c] = sum_kh conj(T[h][kh]) * M2[kh][c], tile 4h x 4c ----
    {
        int h0 = (tid >> 4) * 4;
        int c0 = (tid & 15) * 4;
        float orr[4][4], oii[4][4];
#pragma unroll
        for (int i = 0; i < 4; ++i)
#pragma unroll
            for (int j = 0; j < 4; ++j) { orr[i][j] = 0.f; oii[i][j] = 0.f; }
        for (int kh = 0; kh < 32; ++kh) {
            float2 T0 = sT[h0 + 0][kh];
            float2 T1 = sT[h0 + 1][kh];
            float2 T2 = sT[h0 + 2][kh];
            float2 T3 = sT[h0 + 3][kh];
            float Tr[4] = {T0.x, T1.x, T2.x, T3.x};
            float Ti[4] = {T0.y, T1.y, T2.y, T3.y};
            const float4* tM = (const float4*)(sM2 + kh * 66 + c0);
            float4 m0 = tM[0], m1 = tM[1];
            float Mr[4] = {m0.x, m0.z, m1.x, m1.z};
            float Mi[4] = {m0.y, m0.w, m1.y, m1.w};
#pragma unroll
            for (int i = 0; i < 4; ++i)
#pragma unroll
                for (int j = 0; j < 4; ++j) {
                    orr[i][j] += Tr[i] * Mr[j] + Ti[i] * Mi[j];
                    oii[i][j] += Tr[i] * Mi[j] - Ti[i] * Mr[j];
                }
        }
        float2* dst = (float2*)z2f + (size_t)((b * 8 + kl) * 32 + kw) * 4096;
#pragma unroll
        for (int i = 0; i < 4; ++i) {
            float4* d4 = (float4*)(dst + (h0 + i) * 64 + c0);
            d4[0] = make_float4(orr[i][0], oii[i][0], orr[i][1], oii[i][1]);
            d4[1] = make_float4(orr[i][2], oii[i][2], orr[i][3], oii[i][3]);
        }
    }
}

// ===========================================================================
// K3: fused iDFT-W + iDFT-L + residual.  Block = (b, h, ch); 1024 threads.
__global__ void __launch_bounds__(1024, 4) k3_wl(const float* __restrict__ x,
                                                 const float* __restrict__ z2f,
                                                 float* __restrict__ outp) {
    __shared__ float4 sZ[8 * 32 * 16];   // 64 KB, [kl][kw][cp]
    __shared__ float2 twA[8][64];        // twA[k][l] = (cos,sin)(2pi k l/64)
    int tid = threadIdx.x;
    int bid = blockIdx.x;
    int b = bid >> 7, h = (bid >> 1) & 63, ch = bid & 1;
    int c0 = ch * 32;

    if (tid < 512) {
        int k = tid >> 6, l = tid & 63;
        float s, c;
        sincosf(PI2_64 * (float)((k * l) & 63), &s, &c);
        twA[k][l] = make_float2(c, s);
    }
    const float4* z2 = (const float4*)z2f;
#pragma unroll
    for (int k = 0; k < 4; ++k) {
        int idx = k * 1024 + tid;        // 0..4095 = klkw*16 + cp
        int klkw = idx >> 4, cp = idx & 15;
        sZ[idx] = z2[(size_t)((b * 256 + klkw) * 64 + h) * 32 + ch * 16 + cp];
    }
    __syncthreads();

    int cp = tid & 15, w = tid >> 4;

    // ---- iDFT-W into registers: zw[kl] = sum_kw e^{+2pi i kw w/64} * Z ----
    float4 zw[8];
#pragma unroll
    for (int kl = 0; kl < 8; ++kl) zw[kl] = make_float4(0.f, 0.f, 0.f, 0.f);
    float2 u = make_float2(1.f, 0.f);
    float2 su;
    {
        float s, c;
        sincosf(PI2_64 * (float)w, &s, &c);
        su = make_float2(c, s);          // e^{+2pi i w/64}
    }
    for (int kw = 0; kw < 32; ++kw) {
#pragma unroll
        for (int kl = 0; kl < 8; ++kl) {
            float4 d = sZ[(kl * 32 + kw) * 16 + cp];   // immediate offsets
            zw[kl].x += d.x * u.x - d.y * u.y;
            zw[kl].y += d.y * u.x + d.x * u.y;
            zw[kl].z += d.z * u.x - d.w * u.y;
            zw[kl].w += d.w * u.x + d.z * u.y;
        }
        float nr = u.x * su.x - u.y * su.y;
        float ni = u.y * su.x + u.x * su.y;
        u = make_float2(nr, ni);
    }

    // ---- iDFT-L + residual (numpy irfft: Im(kl=0) dropped, 1..7 doubled) --
    float z0r0 = zw[0].x, z0r1 = zw[0].z;
#pragma unroll
    for (int kl = 1; kl < 8; ++kl) {
        zw[kl].x *= 2.f; zw[kl].y *= 2.f; zw[kl].z *= 2.f; zw[kl].w *= 2.f;
    }
    const float* xp = x + ((size_t)((b * 64 + h) * 64 + w) * 64) * 64 + c0 + 2 * cp;
    float* op = outp + ((size_t)((b * 64 + h) * 64 + w) * 64) * 64 + c0 + 2 * cp;
    const float sc = 1.0f / 512.0f;

    float2 xv0 = *(const float2*)(xp + 0 * 64);
    float2 xv1 = *(const float2*)(xp + 1 * 64);
    float2 xv2 = *(const float2*)(xp + 2 * 64);
    float2 xv3 = *(const float2*)(xp + 3 * 64);
    for (int l0 = 0; l0 < 64; l0 += 4) {
        int lp = (l0 + 4) & 63;          // wraps on last iter (values unused)
        float2 nx0 = *(const float2*)(xp + (lp + 0) * 64);
        float2 nx1 = *(const float2*)(xp + (lp + 1) * 64);
        float2 nx2 = *(const float2*)(xp + (lp + 2) * 64);
        float2 nx3 = *(const float2*)(xp + (lp + 3) * 64);
#pragma unroll
        for (int li = 0; li < 4; ++li) {
            int l = l0 + li;
            float s0 = z0r0, s1 = z0r1;
#pragma unroll
            for (int kl = 1; kl < 8; ++kl) {
                float2 t = twA[kl][l];   // row base + immediate, broadcast
                s0 += zw[kl].x * t.x - zw[kl].y * t.y;
                s1 += zw[kl].z * t.x - zw[kl].w * t.y;
            }
            float2 xv = (li == 0) ? xv0 : (li == 1) ? xv1 : (li == 2) ? xv2 : xv3;
            *(float2*)(op + l * 64) = make_float2(s0 * sc + xv.x, s1 * sc + xv.y);
        }
        xv0 = nx0; xv1 = nx1; xv2 = nx2; xv3 = nx3;
    }
}

// ===========================================================================
extern "C" void kernel_launch(void* const* d_in, const int* in_sizes, int n_in,
                              void* d_out, int out_size, void* d_ws, size_t ws_size,
                              hipStream_t stream) {
    const float* x     = (const float*)d_in[0];
    const float* w1    = (const float*)d_in[1];
    const float* b1    = (const float*)d_in[2];
    const float* w2    = (const float*)d_in[3];
    const float* b2    = (const float*)d_in[4];
    const float* la1rA = (const float*)d_in[5];
    const float* la1rB = (const float*)d_in[6];
    const float* la1iA = (const float*)d_in[7];
    const float* la1iB = (const float*)d_in[8];
    const float* la2rA = (const float*)d_in[9];
    const float* la2rB = (const float*)d_in[10];
    const float* la2iA = (const float*)d_in[11];
    const float* la2iB = (const float*)d_in[12];
    float* out = (float*)d_out;

    float* ws = (float*)d_ws;
    float* y2 = ws;                    // [4][8][32][64][64] complex = 33 MB
    float* z2 = ws + 8388608;          // same

    hipLaunchKernelGGL(k1_lw,    dim3(512),  dim3(1024), 0, stream, x, y2);
    hipLaunchKernelGGL(kc_h_mlp, dim3(1024), dim3(256),  0, stream, y2, z2,
                       w1, b1, w2, b2, la1rA, la1rB, la1iA, la1iB,
                       la2rA, la2rB, la2iA, la2iB);
    hipLaunchKernelGGL(k3_wl,    dim3(512),  dim3(1024), 0, stream, x, z2, out);
}

// Round 6
// 341.072 us; speedup vs baseline: 1.3106x; 1.2867x over previous
//
#include <hip/hip_runtime.h>
#include <math.h>

// ---------------------------------------------------------------------------
// AFNO3D + LoRA, B=4 H=W=L=64 C=64, modes kh<32 kw<32 kl<8, NB=8 BS=8 R=8.
//
// 4-kernel pipeline (intermediates in d_ws):
//   K1a: DFT-L (real->8 modes)   x -> y1[bh][kl][w][c]      (256-thr blocks)
//   K1b: DFT-W (64 -> 32 modes)  y1 -> y2[b][kl][kw][h][c]  (LDS slab GEMM)
//   K2 : DFT-H + block-diag complex MLP (LoRA) + iDFT-H in LDS (validated)
//   K3 : stage z2 slab -> iDFT-W (regs) -> iDFT-L + residual  (validated)
//
// R6 change: k1 un-fused. R4/R5 showed 1024-thread blocks pin VGPR at 64 and
// every ILP attempt spills to scratch (WRITE_SIZE 32->139 MB). K1a/K1b use
// 256-thread blocks, small LDS, ~50 VGPR, many blocks/CU.
// fp32 throughout. Ortho scaling: 1/512 in K2 (pre-MLP) and 1/512 in K3.
// ---------------------------------------------------------------------------

#define PI2_64 0.09817477042468103f   // 2*pi/64

__device__ __forceinline__ float gelu_exact(float t) {
    return 0.5f * t * (1.0f + erff(t * 0.7071067811865475f));
}

// ===========================================================================
// K1a: DFT along L (real -> 8 complex modes).
// Block = (bh, w8): 256 threads = 8 w x 32 c-pairs. Grid 2048.
// y1 float4 layout: [bh][kl][w][cp]  (cp = c/2; float4 = (re0,im0,re1,im1))
__global__ void __launch_bounds__(256) k1a_dft_l(const float* __restrict__ x,
                                                 float* __restrict__ y1f) {
    __shared__ float2 twT[8][64];        // 4 KB: twT[kl][l] = e(+kl*l/64)
    int tid = threadIdx.x;
    {
        int k = tid >> 6, l = tid & 63;
        float s, c;
        sincosf(PI2_64 * (float)((k * l) & 63), &s, &c);
        twT[k][l] = make_float2(c, s);
        int k2 = k + 4;
        sincosf(PI2_64 * (float)((k2 * l) & 63), &s, &c);
        twT[k2][l] = make_float2(c, s);
    }
    __syncthreads();

    int bid = blockIdx.x;                // bh*8 + w8
    int w8 = bid & 7, bh = bid >> 3;
    int cp = tid & 31, wl = tid >> 5;
    int w = w8 * 8 + wl;
    const float* xp = x + (size_t)(bh * 64 + w) * 4096 + 2 * cp;

    float4 A[8];
#pragma unroll
    for (int kl = 0; kl < 8; ++kl) A[kl] = make_float4(0.f, 0.f, 0.f, 0.f);

    for (int l0 = 0; l0 < 64; l0 += 4) {
        float2 v0 = *(const float2*)(xp + (l0 + 0) * 64);
        float2 v1 = *(const float2*)(xp + (l0 + 1) * 64);
        float2 v2 = *(const float2*)(xp + (l0 + 2) * 64);
        float2 v3 = *(const float2*)(xp + (l0 + 3) * 64);
#pragma unroll
        for (int kl = 0; kl < 8; ++kl) {
            float2 t0 = twT[kl][l0 + 0];
            float2 t1 = twT[kl][l0 + 1];
            float2 t2 = twT[kl][l0 + 2];
            float2 t3 = twT[kl][l0 + 3];
            A[kl].x += v0.x * t0.x;  A[kl].y -= v0.x * t0.y;   // e^{-i th}
            A[kl].z += v0.y * t0.x;  A[kl].w -= v0.y * t0.y;
            A[kl].x += v1.x * t1.x;  A[kl].y -= v1.x * t1.y;
            A[kl].z += v1.y * t1.x;  A[kl].w -= v1.y * t1.y;
            A[kl].x += v2.x * t2.x;  A[kl].y -= v2.x * t2.y;
            A[kl].z += v2.y * t2.x;  A[kl].w -= v2.y * t2.y;
            A[kl].x += v3.x * t3.x;  A[kl].y -= v3.x * t3.y;
            A[kl].z += v3.y * t3.x;  A[kl].w -= v3.y * t3.y;
        }
    }
    float4* y1 = (float4*)y1f;
    size_t base = (size_t)bh * 16384 + (size_t)w * 32 + cp;
#pragma unroll
    for (int kl = 0; kl < 8; ++kl)
        y1[base + kl * 2048] = A[kl];
}

// ===========================================================================
// K1b: DFT along W (64 -> 32 modes).  Block = (bh, kl), 256 threads. Grid 2048.
// Stages the contiguous 32 KB y1 slab, reduces over w with a twiddle table.
// Tile: 4 kw x 2 c per thread (lane-contiguous float4 LDS reads).
__global__ void __launch_bounds__(256) k1b_dft_w(const float* __restrict__ y1f,
                                                 float* __restrict__ y2f) {
    __shared__ float4 sD[64 * 32];       // 32 KB  [w][cp]
    __shared__ float2 twT[32][64];       // 16 KB  twT[kw][w] = e(+kw*w/64)
    int tid = threadIdx.x;
#pragma unroll
    for (int e = 0; e < 8; ++e) {
        int idx = e * 256 + tid;
        int k = idx >> 6, l = idx & 63;
        float s, c;
        sincosf(PI2_64 * (float)((k * l) & 63), &s, &c);
        twT[k][l] = make_float2(c, s);
    }
    int pos = blockIdx.x;                // bh*8 + kl
    int kl = pos & 7, bh = pos >> 3;
    const float4* src = (const float4*)y1f + (size_t)pos * 2048;
#pragma unroll
    for (int r = 0; r < 8; ++r)
        sD[r * 256 + tid] = src[r * 256 + tid];
    __syncthreads();

    int cp = tid & 31, kwg = tid >> 5;   // 8 kw-groups of 4
    float4 acc[4];
#pragma unroll
    for (int i = 0; i < 4; ++i) acc[i] = make_float4(0.f, 0.f, 0.f, 0.f);

    for (int w = 0; w < 64; ++w) {
        float4 d = sD[w * 32 + cp];
#pragma unroll
        for (int i = 0; i < 4; ++i) {
            float2 t = twT[kwg * 4 + i][w];
            acc[i].x += d.x * t.x + d.y * t.y;   // * e^{-i th}
            acc[i].y += d.y * t.x - d.x * t.y;
            acc[i].z += d.z * t.x + d.w * t.y;
            acc[i].w += d.w * t.x - d.z * t.y;
        }
    }
    int b = bh >> 6, h = bh & 63;
    float4* y2 = (float4*)y2f;
#pragma unroll
    for (int i = 0; i < 4; ++i) {
        int kw = kwg * 4 + i;
        y2[((size_t)((b * 8 + kl) * 32 + kw) * 64 + h) * 32 + cp] = acc[i];
    }
}

// ===========================================================================
// K2: fused DFT-H (64->32, *1/512) + block-diag complex MLP + iDFT-H (32->64).
// One block per (b,kw,kl). Validated in R2-R5 (unchanged).
__global__ void __launch_bounds__(256) kc_h_mlp(
        const float* __restrict__ y2f, float* __restrict__ z2f,
        const float* __restrict__ w1, const float* __restrict__ b1,
        const float* __restrict__ w2, const float* __restrict__ b2,
        const float* __restrict__ la1rA, const float* __restrict__ la1rB,
        const float* __restrict__ la1iA, const float* __restrict__ la1iB,
        const float* __restrict__ la2rA, const float* __restrict__ la2rB,
        const float* __restrict__ la2iA, const float* __restrict__ la2iB) {
    __shared__ float2 sD[64][64];      // staged input; reused as sM2[32][66]
    __shared__ float2 sT[64][34];      // e^{-2pi i h*kh/64} at [h][kh] (kh<32)
    __shared__ float2 sM[32][66];
    __shared__ float  sW[4][512];
    __shared__ float  sb1[128], sb2[128];
    int tid = threadIdx.x;
    int pos = blockIdx.x;              // (b*32+kw)*8 + kl
    int kl = pos & 7, kw = (pos >> 3) & 31, b = pos >> 8;

#pragma unroll
    for (int r = 0; r < 8; ++r) {
        int idx = r * 256 + tid;
        int h = idx >> 5, kh = idx & 31;
        float sn, cs;
        sincosf(PI2_64 * (float)((h * kh) & 63), &sn, &cs);
        sT[h][kh] = make_float2(cs, -sn);
    }
    const float2* src = (const float2*)y2f + (size_t)((b * 8 + kl) * 32 + kw) * 4096;
#pragma unroll
    for (int r = 0; r < 8; ++r) {
        int f = r * 512 + tid * 2;
        *(float4*)(&sD[f >> 6][f & 63]) = *(const float4*)(src + f);
    }
    {   // LoRA-corrected weights
        const float* As[4]   = {la1rA, la1iA, la2rA, la2iA};
        const float* Bs[4]   = {la1rB, la1iB, la2rB, la2iB};
        const float* base[4] = {w1, w1 + 512, w2, w2 + 512};
#pragma unroll
        for (int e = 0; e < 8; ++e) {
            int flat = tid + e * 256;
            int mat = flat >> 9;
            int rem = flat & 511;
            int n = rem >> 6, i = (rem >> 3) & 7, o = rem & 7;
            const float* A  = As[mat] + n * 64 + i * 8;
            const float* Bp = Bs[mat] + n * 64 + o;
            float s = 0.f;
#pragma unroll
            for (int r = 0; r < 8; ++r) s += A[r] * Bp[r * 8];
            sW[mat][(i * 8 + o) * 8 + n] = base[mat][n * 64 + i * 8 + o] + 0.125f * s;
        }
        if (tid < 128) sb1[tid] = b1[tid];
        else           sb2[tid - 128] = b2[tid - 128];
    }
    __syncthreads();

    // ---- M[kh][c] = (1/512) * sum_h T[h][kh] * D[h][c], tile 4kh x 2c ----
    {
        int kh0 = (tid >> 5) * 4;
        int c0  = (tid & 31) * 2;
        float mr[4][2], mi[4][2];
#pragma unroll
        for (int i = 0; i < 4; ++i)
#pragma unroll
            for (int j = 0; j < 2; ++j) { mr[i][j] = 0.f; mi[i][j] = 0.f; }
        for (int h = 0; h < 64; ++h) {
            const float4* tT = (const float4*)(&sT[h][kh0]);
            float4 u0 = tT[0], u1 = tT[1];
            float4 d0 = *(const float4*)(&sD[h][c0]);
            float Tr[4] = {u0.x, u0.z, u1.x, u1.z};
            float Ti[4] = {u0.y, u0.w, u1.y, u1.w};
            float Dr[2] = {d0.x, d0.z};
            float Di[2] = {d0.y, d0.w};
#pragma unroll
            for (int i = 0; i < 4; ++i)
#pragma unroll
                for (int j = 0; j < 2; ++j) {
                    mr[i][j] += Tr[i] * Dr[j] - Ti[i] * Di[j];
                    mi[i][j] += Tr[i] * Di[j] + Ti[i] * Dr[j];
                }
        }
        const float sc = 1.0f / 512.0f;
#pragma unroll
        for (int i = 0; i < 4; ++i)
#pragma unroll
            for (int j = 0; j < 2; ++j)
                sM[kh0 + i][c0 + j] = make_float2(mr[i][j] * sc, mi[i][j] * sc);
    }
    __syncthreads();

    // ---- MLP per (kh, n) ----
    float2* sM2 = (float2*)&sD[0][0];   // [32][66]
    {
        int kh = tid >> 3, n = tid & 7;
        float xr[8], xi[8];
#pragma unroll
        for (int i = 0; i < 8; ++i) {
            float2 v = sM[kh][n * 8 + i];
            xr[i] = v.x; xi[i] = v.y;
        }
        float o1r[8], o1i[8];
#pragma unroll
        for (int o = 0; o < 8; ++o) {
            float br = sb1[n * 8 + o], bi = sb1[64 + n * 8 + o];
            float sr = br - bi, si = br + bi;
#pragma unroll
            for (int i = 0; i < 8; ++i) {
                float wr = sW[0][(i * 8 + o) * 8 + n];
                float wi = sW[1][(i * 8 + o) * 8 + n];
                sr += xr[i] * wr - xi[i] * wi;
                si += xi[i] * wr + xr[i] * wi;
            }
            o1r[o] = gelu_exact(sr);
            o1i[o] = gelu_exact(si);
        }
#pragma unroll
        for (int o = 0; o < 8; ++o) {
            float br = sb2[n * 8 + o], bi = sb2[64 + n * 8 + o];
            float sr = br - bi, si = br + bi;
#pragma unroll
            for (int i = 0; i < 8; ++i) {
                float wr = sW[2][(i * 8 + o) * 8 + n];
                float wi = sW[3][(i * 8 + o) * 8 + n];
                sr += o1r[i] * wr - o1i[i] * wi;
                si += o1i[i] * wr + o1r[i] * wi;
            }
            sM2[kh * 66 + n * 8 + o] = make_float2(sr, si);
        }
    }
    __syncthreads();

    // ---- out[h][c] = sum_kh conj(T[h][kh]) * M2[kh][c], tile 4h x 4c ----
    {
        int h0 = (tid >> 4) * 4;
        int c0 = (tid & 15) * 4;
        float orr[4][4], oii[4][4];
#pragma unroll
        for (int i = 0; i < 4; ++i)
#pragma unroll
            for (int j = 0; j < 4; ++j) { orr[i][j] = 0.f; oii[i][j] = 0.f; }
        for (int kh = 0; kh < 32; ++kh) {
            float2 T0 = sT[h0 + 0][kh];
            float2 T1 = sT[h0 + 1][kh];
            float2 T2 = sT[h0 + 2][kh];
            float2 T3 = sT[h0 + 3][kh];
            float Tr[4] = {T0.x, T1.x, T2.x, T3.x};
            float Ti[4] = {T0.y, T1.y, T2.y, T3.y};
            const float4* tM = (const float4*)(sM2 + kh * 66 + c0);
            float4 m0 = tM[0], m1 = tM[1];
            float Mr[4] = {m0.x, m0.z, m1.x, m1.z};
            float Mi[4] = {m0.y, m0.w, m1.y, m1.w};
#pragma unroll
            for (int i = 0; i < 4; ++i)
#pragma unroll
                for (int j = 0; j < 4; ++j) {
                    orr[i][j] += Tr[i] * Mr[j] + Ti[i] * Mi[j];
                    oii[i][j] += Tr[i] * Mi[j] - Ti[i] * Mr[j];
                }
        }
        float2* dst = (float2*)z2f + (size_t)((b * 8 + kl) * 32 + kw) * 4096;
#pragma unroll
        for (int i = 0; i < 4; ++i) {
            float4* d4 = (float4*)(dst + (h0 + i) * 64 + c0);
            d4[0] = make_float4(orr[i][0], oii[i][0], orr[i][1], oii[i][1]);
            d4[1] = make_float4(orr[i][2], oii[i][2], orr[i][3], oii[i][3]);
        }
    }
}

// ===========================================================================
// K3: fused iDFT-W + iDFT-L + residual.  Block = (b, h, ch); 1024 threads.
// Validated in R5 (unchanged).
__global__ void __launch_bounds__(1024, 4) k3_wl(const float* __restrict__ x,
                                                 const float* __restrict__ z2f,
                                                 float* __restrict__ outp) {
    __shared__ float4 sZ[8 * 32 * 16];   // 64 KB, [kl][kw][cp]
    __shared__ float2 twA[8][64];        // twA[k][l] = (cos,sin)(2pi k l/64)
    int tid = threadIdx.x;
    int bid = blockIdx.x;
    int b = bid >> 7, h = (bid >> 1) & 63, ch = bid & 1;
    int c0 = ch * 32;

    if (tid < 512) {
        int k = tid >> 6, l = tid & 63;
        float s, c;
        sincosf(PI2_64 * (float)((k * l) & 63), &s, &c);
        twA[k][l] = make_float2(c, s);
    }
    const float4* z2 = (const float4*)z2f;
#pragma unroll
    for (int k = 0; k < 4; ++k) {
        int idx = k * 1024 + tid;        // 0..4095 = klkw*16 + cp
        int klkw = idx >> 4, cp = idx & 15;
        sZ[idx] = z2[(size_t)((b * 256 + klkw) * 64 + h) * 32 + ch * 16 + cp];
    }
    __syncthreads();

    int cp = tid & 15, w = tid >> 4;

    // ---- iDFT-W into registers: zw[kl] = sum_kw e^{+2pi i kw w/64} * Z ----
    float4 zw[8];
#pragma unroll
    for (int kl = 0; kl < 8; ++kl) zw[kl] = make_float4(0.f, 0.f, 0.f, 0.f);
    float2 u = make_float2(1.f, 0.f);
    float2 su;
    {
        float s, c;
        sincosf(PI2_64 * (float)w, &s, &c);
        su = make_float2(c, s);          // e^{+2pi i w/64}
    }
    for (int kw = 0; kw < 32; ++kw) {
#pragma unroll
        for (int kl = 0; kl < 8; ++kl) {
            float4 d = sZ[(kl * 32 + kw) * 16 + cp];   // immediate offsets
            zw[kl].x += d.x * u.x - d.y * u.y;
            zw[kl].y += d.y * u.x + d.x * u.y;
            zw[kl].z += d.z * u.x - d.w * u.y;
            zw[kl].w += d.w * u.x + d.z * u.y;
        }
        float nr = u.x * su.x - u.y * su.y;
        float ni = u.y * su.x + u.x * su.y;
        u = make_float2(nr, ni);
    }

    // ---- iDFT-L + residual (numpy irfft: Im(kl=0) dropped, 1..7 doubled) --
    float z0r0 = zw[0].x, z0r1 = zw[0].z;
#pragma unroll
    for (int kl = 1; kl < 8; ++kl) {
        zw[kl].x *= 2.f; zw[kl].y *= 2.f; zw[kl].z *= 2.f; zw[kl].w *= 2.f;
    }
    const float* xp = x + ((size_t)((b * 64 + h) * 64 + w) * 64) * 64 + c0 + 2 * cp;
    float* op = outp + ((size_t)((b * 64 + h) * 64 + w) * 64) * 64 + c0 + 2 * cp;
    const float sc = 1.0f / 512.0f;

    float2 xv0 = *(const float2*)(xp + 0 * 64);
    float2 xv1 = *(const float2*)(xp + 1 * 64);
    float2 xv2 = *(const float2*)(xp + 2 * 64);
    float2 xv3 = *(const float2*)(xp + 3 * 64);
    for (int l0 = 0; l0 < 64; l0 += 4) {
        int lp = (l0 + 4) & 63;          // wraps on last iter (values unused)
        float2 nx0 = *(const float2*)(xp + (lp + 0) * 64);
        float2 nx1 = *(const float2*)(xp + (lp + 1) * 64);
        float2 nx2 = *(const float2*)(xp + (lp + 2) * 64);
        float2 nx3 = *(const float2*)(xp + (lp + 3) * 64);
#pragma unroll
        for (int li = 0; li < 4; ++li) {
            int l = l0 + li;
            float s0 = z0r0, s1 = z0r1;
#pragma unroll
            for (int kl = 1; kl < 8; ++kl) {
                float2 t = twA[kl][l];   // row base + immediate, broadcast
                s0 += zw[kl].x * t.x - zw[kl].y * t.y;
                s1 += zw[kl].z * t.x - zw[kl].w * t.y;
            }
            float2 xv = (li == 0) ? xv0 : (li == 1) ? xv1 : (li == 2) ? xv2 : xv3;
            *(float2*)(op + l * 64) = make_float2(s0 * sc + xv.x, s1 * sc + xv.y);
        }
        xv0 = nx0; xv1 = nx1; xv2 = nx2; xv3 = nx3;
    }
}

// ===========================================================================
extern "C" void kernel_launch(void* const* d_in, const int* in_sizes, int n_in,
                              void* d_out, int out_size, void* d_ws, size_t ws_size,
                              hipStream_t stream) {
    const float* x     = (const float*)d_in[0];
    const float* w1    = (const float*)d_in[1];
    const float* b1    = (const float*)d_in[2];
    const float* w2    = (const float*)d_in[3];
    const float* b2    = (const float*)d_in[4];
    const float* la1rA = (const float*)d_in[5];
    const float* la1rB = (const float*)d_in[6];
    const float* la1iA = (const float*)d_in[7];
    const float* la1iB = (const float*)d_in[8];
    const float* la2rA = (const float*)d_in[9];
    const float* la2rB = (const float*)d_in[10];
    const float* la2iA = (const float*)d_in[11];
    const float* la2iB = (const float*)d_in[12];
    float* out = (float*)d_out;

    float* ws = (float*)d_ws;
    float* y1 = ws;                    // [256 bh][8 kl][64 w][32 cp] f4 = 67 MB
    float* y2 = ws + 16777216;         // [4][8][32][64][64] complex = 33 MB
    float* z2 = ws + 25165824;         // same as y2

    hipLaunchKernelGGL(k1a_dft_l, dim3(2048), dim3(256),  0, stream, x, y1);
    hipLaunchKernelGGL(k1b_dft_w, dim3(2048), dim3(256),  0, stream, y1, y2);
    hipLaunchKernelGGL(kc_h_mlp,  dim3(1024), dim3(256),  0, stream, y2, z2,
                       w1, b1, w2, b2, la1rA, la1rB, la1iA, la1iB,
                       la2rA, la2rB, la2iA, la2iB);
    hipLaunchKernelGGL(k3_wl,     dim3(512),  dim3(1024), 0, stream, x, z2, out);
}

// Round 7
// 338.070 us; speedup vs baseline: 1.3222x; 1.0089x over previous
//
#include <hip/hip_runtime.h>
#include <math.h>

// ---------------------------------------------------------------------------
// AFNO3D + LoRA, B=4 H=W=L=64 C=64, modes kh<32 kw<32 kl<8, NB=8 BS=8 R=8.
//
// 4-kernel pipeline (intermediates in d_ws):
//   K1a: DFT-L (real->8 modes)   x -> y1[bh][kl][w][c]      (validated R6)
//   K1b: DFT-W (64 -> 32 modes)  y1 -> y2[b][kl][kw][h][c]  (validated R6)
//   K2 : DFT-H + block-diag complex MLP (LoRA) + iDFT-H in LDS (validated)
//   K3 : stage z2 slab -> iDFT-W (regs) -> iDFT-L + residual
//
// R7 change: K3 restructured 1024-thr -> 512-thr (2 w-rows per thread).
//   - 512-thr blocks allow 128 VGPR (1024-thr pinned 64 -> R4/R5-style spill
//     risk); __launch_bounds__(512,4), 68 KB LDS, 2 blocks/CU.
//   - even/odd-kw accumulators: u(kw,w+32) = u(kw,w)*(-1)^kw, so
//     zA = zE+zO, zB = zE-zO — halves iDFT-W FLOPs, shares all LDS reads.
//   - clean 2-deep x prefetch (no select chain).
// fp32 throughout. Ortho scaling: 1/512 in K2 (pre-MLP) and 1/512 in K3.
// ---------------------------------------------------------------------------

#define PI2_64 0.09817477042468103f   // 2*pi/64

__device__ __forceinline__ float gelu_exact(float t) {
    return 0.5f * t * (1.0f + erff(t * 0.7071067811865475f));
}

// ===========================================================================
// K1a: DFT along L (real -> 8 complex modes).
// Block = (bh, w8): 256 threads = 8 w x 32 c-pairs. Grid 2048.
// y1 float4 layout: [bh][kl][w][cp]  (cp = c/2; float4 = (re0,im0,re1,im1))
__global__ void __launch_bounds__(256) k1a_dft_l(const float* __restrict__ x,
                                                 float* __restrict__ y1f) {
    __shared__ float2 twT[8][64];        // 4 KB: twT[kl][l] = e(+kl*l/64)
    int tid = threadIdx.x;
    {
        int k = tid >> 6, l = tid & 63;
        float s, c;
        sincosf(PI2_64 * (float)((k * l) & 63), &s, &c);
        twT[k][l] = make_float2(c, s);
        int k2 = k + 4;
        sincosf(PI2_64 * (float)((k2 * l) & 63), &s, &c);
        twT[k2][l] = make_float2(c, s);
    }
    __syncthreads();

    int bid = blockIdx.x;                // bh*8 + w8
    int w8 = bid & 7, bh = bid >> 3;
    int cp = tid & 31, wl = tid >> 5;
    int w = w8 * 8 + wl;
    const float* xp = x + (size_t)(bh * 64 + w) * 4096 + 2 * cp;

    float4 A[8];
#pragma unroll
    for (int kl = 0; kl < 8; ++kl) A[kl] = make_float4(0.f, 0.f, 0.f, 0.f);

    for (int l0 = 0; l0 < 64; l0 += 4) {
        float2 v0 = *(const float2*)(xp + (l0 + 0) * 64);
        float2 v1 = *(const float2*)(xp + (l0 + 1) * 64);
        float2 v2 = *(const float2*)(xp + (l0 + 2) * 64);
        float2 v3 = *(const float2*)(xp + (l0 + 3) * 64);
#pragma unroll
        for (int kl = 0; kl < 8; ++kl) {
            float2 t0 = twT[kl][l0 + 0];
            float2 t1 = twT[kl][l0 + 1];
            float2 t2 = twT[kl][l0 + 2];
            float2 t3 = twT[kl][l0 + 3];
            A[kl].x += v0.x * t0.x;  A[kl].y -= v0.x * t0.y;   // e^{-i th}
            A[kl].z += v0.y * t0.x;  A[kl].w -= v0.y * t0.y;
            A[kl].x += v1.x * t1.x;  A[kl].y -= v1.x * t1.y;
            A[kl].z += v1.y * t1.x;  A[kl].w -= v1.y * t1.y;
            A[kl].x += v2.x * t2.x;  A[kl].y -= v2.x * t2.y;
            A[kl].z += v2.y * t2.x;  A[kl].w -= v2.y * t2.y;
            A[kl].x += v3.x * t3.x;  A[kl].y -= v3.x * t3.y;
            A[kl].z += v3.y * t3.x;  A[kl].w -= v3.y * t3.y;
        }
    }
    float4* y1 = (float4*)y1f;
    size_t base = (size_t)bh * 16384 + (size_t)w * 32 + cp;
#pragma unroll
    for (int kl = 0; kl < 8; ++kl)
        y1[base + kl * 2048] = A[kl];
}

// ===========================================================================
// K1b: DFT along W (64 -> 32 modes).  Block = (bh, kl), 256 threads. Grid 2048.
__global__ void __launch_bounds__(256) k1b_dft_w(const float* __restrict__ y1f,
                                                 float* __restrict__ y2f) {
    __shared__ float4 sD[64 * 32];       // 32 KB  [w][cp]
    __shared__ float2 twT[32][64];       // 16 KB  twT[kw][w] = e(+kw*w/64)
    int tid = threadIdx.x;
#pragma unroll
    for (int e = 0; e < 8; ++e) {
        int idx = e * 256 + tid;
        int k = idx >> 6, l = idx & 63;
        float s, c;
        sincosf(PI2_64 * (float)((k * l) & 63), &s, &c);
        twT[k][l] = make_float2(c, s);
    }
    int pos = blockIdx.x;                // bh*8 + kl
    int kl = pos & 7, bh = pos >> 3;
    const float4* src = (const float4*)y1f + (size_t)pos * 2048;
#pragma unroll
    for (int r = 0; r < 8; ++r)
        sD[r * 256 + tid] = src[r * 256 + tid];
    __syncthreads();

    int cp = tid & 31, kwg = tid >> 5;   // 8 kw-groups of 4
    float4 acc[4];
#pragma unroll
    for (int i = 0; i < 4; ++i) acc[i] = make_float4(0.f, 0.f, 0.f, 0.f);

    for (int w = 0; w < 64; ++w) {
        float4 d = sD[w * 32 + cp];
#pragma unroll
        for (int i = 0; i < 4; ++i) {
            float2 t = twT[kwg * 4 + i][w];
            acc[i].x += d.x * t.x + d.y * t.y;   // * e^{-i th}
            acc[i].y += d.y * t.x - d.x * t.y;
            acc[i].z += d.z * t.x + d.w * t.y;
            acc[i].w += d.w * t.x - d.z * t.y;
        }
    }
    int b = bh >> 6, h = bh & 63;
    float4* y2 = (float4*)y2f;
#pragma unroll
    for (int i = 0; i < 4; ++i) {
        int kw = kwg * 4 + i;
        y2[((size_t)((b * 8 + kl) * 32 + kw) * 64 + h) * 32 + cp] = acc[i];
    }
}

// ===========================================================================
// K2: fused DFT-H (64->32, *1/512) + block-diag complex MLP + iDFT-H (32->64).
// One block per (b,kw,kl). Validated in R2-R6 (unchanged).
__global__ void __launch_bounds__(256) kc_h_mlp(
        const float* __restrict__ y2f, float* __restrict__ z2f,
        const float* __restrict__ w1, const float* __restrict__ b1,
        const float* __restrict__ w2, const float* __restrict__ b2,
        const float* __restrict__ la1rA, const float* __restrict__ la1rB,
        const float* __restrict__ la1iA, const float* __restrict__ la1iB,
        const float* __restrict__ la2rA, const float* __restrict__ la2rB,
        const float* __restrict__ la2iA, const float* __restrict__ la2iB) {
    __shared__ float2 sD[64][64];      // staged input; reused as sM2[32][66]
    __shared__ float2 sT[64][34];      // e^{-2pi i h*kh/64} at [h][kh] (kh<32)
    __shared__ float2 sM[32][66];
    __shared__ float  sW[4][512];
    __shared__ float  sb1[128], sb2[128];
    int tid = threadIdx.x;
    int pos = blockIdx.x;              // (b*32+kw)*8 + kl
    int kl = pos & 7, kw = (pos >> 3) & 31, b = pos >> 8;

#pragma unroll
    for (int r = 0; r < 8; ++r) {
        int idx = r * 256 + tid;
        int h = idx >> 5, kh = idx & 31;
        float sn, cs;
        sincosf(PI2_64 * (float)((h * kh) & 63), &sn, &cs);
        sT[h][kh] = make_float2(cs, -sn);
    }
    const float2* src = (const float2*)y2f + (size_t)((b * 8 + kl) * 32 + kw) * 4096;
#pragma unroll
    for (int r = 0; r < 8; ++r) {
        int f = r * 512 + tid * 2;
        *(float4*)(&sD[f >> 6][f & 63]) = *(const float4*)(src + f);
    }
    {   // LoRA-corrected weights
        const float* As[4]   = {la1rA, la1iA, la2rA, la2iA};
        const float* Bs[4]   = {la1rB, la1iB, la2rB, la2iB};
        const float* base[4] = {w1, w1 + 512, w2, w2 + 512};
#pragma unroll
        for (int e = 0; e < 8; ++e) {
            int flat = tid + e * 256;
            int mat = flat >> 9;
            int rem = flat & 511;
            int n = rem >> 6, i = (rem >> 3) & 7, o = rem & 7;
            const float* A  = As[mat] + n * 64 + i * 8;
            const float* Bp = Bs[mat] + n * 64 + o;
            float s = 0.f;
#pragma unroll
            for (int r = 0; r < 8; ++r) s += A[r] * Bp[r * 8];
            sW[mat][(i * 8 + o) * 8 + n] = base[mat][n * 64 + i * 8 + o] + 0.125f * s;
        }
        if (tid < 128) sb1[tid] = b1[tid];
        else           sb2[tid - 128] = b2[tid - 128];
    }
    __syncthreads();

    // ---- M[kh][c] = (1/512) * sum_h T[h][kh] * D[h][c], tile 4kh x 2c ----
    {
        int kh0 = (tid >> 5) * 4;
        int c0  = (tid & 31) * 2;
        float mr[4][2], mi[4][2];
#pragma unroll
        for (int i = 0; i < 4; ++i)
#pragma unroll
            for (int j = 0; j < 2; ++j) { mr[i][j] = 0.f; mi[i][j] = 0.f; }
        for (int h = 0; h < 64; ++h) {
            const float4* tT = (const float4*)(&sT[h][kh0]);
            float4 u0 = tT[0], u1 = tT[1];
            float4 d0 = *(const float4*)(&sD[h][c0]);
            float Tr[4] = {u0.x, u0.z, u1.x, u1.z};
            float Ti[4] = {u0.y, u0.w, u1.y, u1.w};
            float Dr[2] = {d0.x, d0.z};
            float Di[2] = {d0.y, d0.w};
#pragma unroll
            for (int i = 0; i < 4; ++i)
#pragma unroll
                for (int j = 0; j < 2; ++j) {
                    mr[i][j] += Tr[i] * Dr[j] - Ti[i] * Di[j];
                    mi[i][j] += Tr[i] * Di[j] + Ti[i] * Dr[j];
                }
        }
        const float sc = 1.0f / 512.0f;
#pragma unroll
        for (int i = 0; i < 4; ++i)
#pragma unroll
            for (int j = 0; j < 2; ++j)
                sM[kh0 + i][c0 + j] = make_float2(mr[i][j] * sc, mi[i][j] * sc);
    }
    __syncthreads();

    // ---- MLP per (kh, n) ----
    float2* sM2 = (float2*)&sD[0][0];   // [32][66]
    {
        int kh = tid >> 3, n = tid & 7;
        float xr[8], xi[8];
#pragma unroll
        for (int i = 0; i < 8; ++i) {
            float2 v = sM[kh][n * 8 + i];
            xr[i] = v.x; xi[i] = v.y;
        }
        float o1r[8], o1i[8];
#pragma unroll
        for (int o = 0; o < 8; ++o) {
            float br = sb1[n * 8 + o], bi = sb1[64 + n * 8 + o];
            float sr = br - bi, si = br + bi;
#pragma unroll
            for (int i = 0; i < 8; ++i) {
                float wr = sW[0][(i * 8 + o) * 8 + n];
                float wi = sW[1][(i * 8 + o) * 8 + n];
                sr += xr[i] * wr - xi[i] * wi;
                si += xi[i] * wr + xr[i] * wi;
            }
            o1r[o] = gelu_exact(sr);
            o1i[o] = gelu_exact(si);
        }
#pragma unroll
        for (int o = 0; o < 8; ++o) {
            float br = sb2[n * 8 + o], bi = sb2[64 + n * 8 + o];
            float sr = br - bi, si = br + bi;
#pragma unroll
            for (int i = 0; i < 8; ++i) {
                float wr = sW[2][(i * 8 + o) * 8 + n];
                float wi = sW[3][(i * 8 + o) * 8 + n];
                sr += o1r[i] * wr - o1i[i] * wi;
                si += o1i[i] * wr + o1r[i] * wi;
            }
            sM2[kh * 66 + n * 8 + o] = make_float2(sr, si);
        }
    }
    __syncthreads();

    // ---- out[h][c] = sum_kh conj(T[h][kh]) * M2[kh][c], tile 4h x 4c ----
    {
        int h0 = (tid >> 4) * 4;
        int c0 = (tid & 15) * 4;
        float orr[4][4], oii[4][4];
#pragma unroll
        for (int i = 0; i < 4; ++i)
#pragma unroll
            for (int j = 0; j < 4; ++j) { orr[i][j] = 0.f; oii[i][j] = 0.f; }
        for (int kh = 0; kh < 32; ++kh) {
            float2 T0 = sT[h0 + 0][kh];
            float2 T1 = sT[h0 + 1][kh];
            float2 T2 = sT[h0 + 2][kh];
            float2 T3 = sT[h0 + 3][kh];
            float Tr[4] = {T0.x, T1.x, T2.x, T3.x};
            float Ti[4] = {T0.y, T1.y, T2.y, T3.y};
            const float4* tM = (const float4*)(sM2 + kh * 66 + c0);
            float4 m0 = tM[0], m1 = tM[1];
            float Mr[4] = {m0.x, m0.z, m1.x, m1.z};
            float Mi[4] = {m0.y, m0.w, m1.y, m1.w};
#pragma unroll
            for (int i = 0; i < 4; ++i)
#pragma unroll
                for (int j = 0; j < 4; ++j) {
                    orr[i][j] += Tr[i] * Mr[j] + Ti[i] * Mi[j];
                    oii[i][j] += Tr[i] * Mi[j] - Ti[i] * Mr[j];
                }
        }
        float2* dst = (float2*)z2f + (size_t)((b * 8 + kl) * 32 + kw) * 4096;
#pragma unroll
        for (int i = 0; i < 4; ++i) {
            float4* d4 = (float4*)(dst + (h0 + i) * 64 + c0);
            d4[0] = make_float4(orr[i][0], oii[i][0], orr[i][1], oii[i][1]);
            d4[1] = make_float4(orr[i][2], oii[i][2], orr[i][3], oii[i][3]);
        }
    }
}

// ===========================================================================
// K3: fused iDFT-W + iDFT-L + residual.  Block = (b, h, ch); 512 threads.
// Thread (wlo = tid>>4 in [0,32), cp = tid&15) handles rows w=wlo and wlo+32.
// Even/odd-kw accumulators: zA = zE+zO (w), zB = zE-zO (w+32).
__global__ void __launch_bounds__(512, 4) k3_wl(const float* __restrict__ x,
                                                const float* __restrict__ z2f,
                                                float* __restrict__ outp) {
    __shared__ float4 sZ[8 * 32 * 16];   // 64 KB, [kl][kw][cp]
    __shared__ float2 twA[8][64];        // 4 KB: twA[k][l] = e(+k*l/64)
    int tid = threadIdx.x;
    int bid = blockIdx.x;
    int b = bid >> 7, h = (bid >> 1) & 63, ch = bid & 1;
    int c0 = ch * 32;

    {
        int k = tid >> 6, l = tid & 63;   // tid<512 covers all 8x64
        float s, c;
        sincosf(PI2_64 * (float)((k * l) & 63), &s, &c);
        twA[k][l] = make_float2(c, s);
    }
    const float4* z2 = (const float4*)z2f;
#pragma unroll
    for (int k = 0; k < 8; ++k) {
        int idx = k * 512 + tid;         // 0..4095 = klkw*16 + cp
        int klkw = idx >> 4, cp = idx & 15;
        sZ[idx] = z2[(size_t)((b * 256 + klkw) * 64 + h) * 32 + ch * 16 + cp];
    }
    __syncthreads();

    int cp = tid & 15, wlo = tid >> 4;   // wlo in [0,32)

    // ---- iDFT-W: zE/zO = even/odd-kw partial sums (shared for both rows) --
    float4 zE[8], zO[8];
#pragma unroll
    for (int kl = 0; kl < 8; ++kl) {
        zE[kl] = make_float4(0.f, 0.f, 0.f, 0.f);
        zO[kl] = make_float4(0.f, 0.f, 0.f, 0.f);
    }
    float2 u = make_float2(1.f, 0.f);
    float2 su;
    {
        float s, c;
        sincosf(PI2_64 * (float)wlo, &s, &c);
        su = make_float2(c, s);          // e^{+2pi i wlo/64}
    }
    for (int kw = 0; kw < 32; kw += 2) {
        // even kw
#pragma unroll
        for (int kl = 0; kl < 8; ++kl) {
            float4 d = sZ[(kl * 32 + kw) * 16 + cp];
            zE[kl].x += d.x * u.x - d.y * u.y;
            zE[kl].y += d.y * u.x + d.x * u.y;
            zE[kl].z += d.z * u.x - d.w * u.y;
            zE[kl].w += d.w * u.x + d.z * u.y;
        }
        {
            float nr = u.x * su.x - u.y * su.y;
            float ni = u.y * su.x + u.x * su.y;
            u = make_float2(nr, ni);
        }
        // odd kw
#pragma unroll
        for (int kl = 0; kl < 8; ++kl) {
            float4 d = sZ[(kl * 32 + kw + 1) * 16 + cp];
            zO[kl].x += d.x * u.x - d.y * u.y;
            zO[kl].y += d.y * u.x + d.x * u.y;
            zO[kl].z += d.z * u.x - d.w * u.y;
            zO[kl].w += d.w * u.x + d.z * u.y;
        }
        {
            float nr = u.x * su.x - u.y * su.y;
            float ni = u.y * su.x + u.x * su.y;
            u = make_float2(nr, ni);
        }
    }
    // zA (row w=wlo) = zE+zO ; zB (row w=wlo+32) = zE-zO.  Reuse zE/zO regs.
#pragma unroll
    for (int kl = 0; kl < 8; ++kl) {
        float4 e = zE[kl], o = zO[kl];
        zE[kl] = make_float4(e.x + o.x, e.y + o.y, e.z + o.z, e.w + o.w);  // zA
        zO[kl] = make_float4(e.x - o.x, e.y - o.y, e.z - o.z, e.w - o.w);  // zB
    }

    // ---- iDFT-L + residual (numpy irfft: Im(kl=0) dropped, 1..7 doubled) --
    float zAr0 = zE[0].x, zAr1 = zE[0].z;
    float zBr0 = zO[0].x, zBr1 = zO[0].z;
#pragma unroll
    for (int kl = 1; kl < 8; ++kl) {
        zE[kl].x *= 2.f; zE[kl].y *= 2.f; zE[kl].z *= 2.f; zE[kl].w *= 2.f;
        zO[kl].x *= 2.f; zO[kl].y *= 2.f; zO[kl].z *= 2.f; zO[kl].w *= 2.f;
    }
    const size_t rowA = (size_t)((b * 64 + h) * 64 + wlo) * 4096;
    const size_t rowB = rowA + (size_t)32 * 4096;
    const float* xpA = x + rowA + c0 + 2 * cp;
    const float* xpB = x + rowB + c0 + 2 * cp;
    float* opA = outp + rowA + c0 + 2 * cp;
    float* opB = outp + rowB + c0 + 2 * cp;
    const float sc = 1.0f / 512.0f;

    // 2-deep prefetch of x for both rows
    float2 a0 = *(const float2*)(xpA + 0 * 64);
    float2 b0 = *(const float2*)(xpB + 0 * 64);
    float2 a1 = *(const float2*)(xpA + 1 * 64);
    float2 b1 = *(const float2*)(xpB + 1 * 64);
    for (int l = 0; l < 64; ++l) {
        int lp = (l + 2) & 63;           // wraps on last 2 iters (unused)
        float2 a2 = *(const float2*)(xpA + lp * 64);
        float2 b2 = *(const float2*)(xpB + lp * 64);
        float s0 = zAr0, s1 = zAr1, s2 = zBr0, s3 = zBr1;
#pragma unroll
        for (int kl = 1; kl < 8; ++kl) {
            float2 t = twA[kl][l];       // row base + immediate, broadcast
            s0 += zE[kl].x * t.x - zE[kl].y * t.y;
            s1 += zE[kl].z * t.x - zE[kl].w * t.y;
            s2 += zO[kl].x * t.x - zO[kl].y * t.y;
            s3 += zO[kl].z * t.x - zO[kl].w * t.y;
        }
        *(float2*)(opA + l * 64) = make_float2(s0 * sc + a0.x, s1 * sc + a0.y);
        *(float2*)(opB + l * 64) = make_float2(s2 * sc + b0.x, s3 * sc + b0.y);
        a0 = a1; a1 = a2; b0 = b1; b1 = b2;
    }
}

// ===========================================================================
extern "C" void kernel_launch(void* const* d_in, const int* in_sizes, int n_in,
                              void* d_out, int out_size, void* d_ws, size_t ws_size,
                              hipStream_t stream) {
    const float* x     = (const float*)d_in[0];
    const float* w1    = (const float*)d_in[1];
    const float* b1    = (const float*)d_in[2];
    const float* w2    = (const float*)d_in[3];
    const float* b2    = (const float*)d_in[4];
    const float* la1rA = (const float*)d_in[5];
    const float* la1rB = (const float*)d_in[6];
    const float* la1iA = (const float*)d_in[7];
    const float* la1iB = (const float*)d_in[8];
    const float* la2rA = (const float*)d_in[9];
    const float* la2rB = (const float*)d_in[10];
    const float* la2iA = (const float*)d_in[11];
    const float* la2iB = (const float*)d_in[12];
    float* out = (float*)d_out;

    float* ws = (float*)d_ws;
    float* y1 = ws;                    // [256 bh][8 kl][64 w][32 cp] f4 = 67 MB
    float* y2 = ws + 16777216;         // [4][8][32][64][64] complex = 33 MB
    float* z2 = ws + 25165824;         // same as y2

    hipLaunchKernelGGL(k1a_dft_l, dim3(2048), dim3(256), 0, stream, x, y1);
    hipLaunchKernelGGL(k1b_dft_w, dim3(2048), dim3(256), 0, stream, y1, y2);
    hipLaunchKernelGGL(kc_h_mlp,  dim3(1024), dim3(256), 0, stream, y2, z2,
                       w1, b1, w2, b2, la1rA, la1rB, la1iA, la1iB,
                       la2rA, la2rB, la2iA, la2iB);
    hipLaunchKernelGGL(k3_wl,     dim3(512),  dim3(512), 0, stream, x, z2, out);
}